// Round 2
// baseline (1253.210 us; speedup 1.0000x reference)
//
#include <hip/hip_runtime.h>

#define N_NODES 50000
#define N_EDGES 625000
#define D       128
#define TWO_D   256
#define TM      64      // rows (edges or nodes) per block
#define THREADS 256

typedef short  s8v  __attribute__((ext_vector_type(8)));   // 8 bf16 (4 VGPRs)
typedef float  f4v  __attribute__((ext_vector_type(4)));   // 4 f32 acc
typedef unsigned short ushort_t;
typedef unsigned int   uint_t;

// ---- fp32 <-> bf16 (RNE) helpers, bit-level (no __bf16 type dependence) ----
static __device__ __forceinline__ ushort_t f2bf(float f) {
    uint_t u = __builtin_bit_cast(uint_t, f);
    u = (u + 0x7FFFu + ((u >> 16) & 1u)) >> 16;
    return (ushort_t)u;
}
static __device__ __forceinline__ float bf2f(ushort_t h) {
    uint_t u = ((uint_t)h) << 16;
    return __builtin_bit_cast(float, u);
}

// ---------------------------------------------------------------------------
// Prep: transpose + hi/lo-split W1 [256x128] and W2 [128x128] into d_ws.
//   w1t_hi/lo : [128 n][256 k] bf16 (ushort)
//   w2t_hi/lo : [128 n][128 k]
// ---------------------------------------------------------------------------
__global__ void prep_weights(const float* __restrict__ W1,
                             const float* __restrict__ W2,
                             ushort_t* __restrict__ w1t_hi,
                             ushort_t* __restrict__ w1t_lo,
                             ushort_t* __restrict__ w2t_hi,
                             ushort_t* __restrict__ w2t_lo)
{
    int t = blockIdx.x * 256 + threadIdx.x;
    if (t < 128 * 256) {
        int n = t >> 8, k = t & 255;
        float w = W1[k * D + n];
        ushort_t h = f2bf(w);
        w1t_hi[n * 256 + k] = h;
        w1t_lo[n * 256 + k] = f2bf(w - bf2f(h));
    } else if (t < 128 * 256 + 128 * 128) {
        int u = t - 128 * 256;
        int n = u >> 7, k = u & 127;
        float w = W2[k * D + n];
        ushort_t h = f2bf(w);
        w2t_hi[n * 128 + k] = h;
        w2t_lo[n * 128 + k] = f2bf(w - bf2f(h));
    }
}

// ---------------------------------------------------------------------------
// MFMA edge kernel (bf16x3 split precision).
// Block: 64 edges, 256 thr = 4 waves (2x2). LDS 64 KB:
//   Xhi [64][256] bf16 @0, Xlo @32768. After layer-1, H (hi@0, lo@16384)
//   overwrites dead X storage (barrier-separated).
// Swizzle: byte_addr ^= (row&7)<<4 on every LDS access (both sides).
// ---------------------------------------------------------------------------
__global__ __launch_bounds__(THREADS, 2)
void edge_kernel_mfma(const float* __restrict__ node_latents,
                      const float* __restrict__ edge_latents,
                      const int*   __restrict__ senders,
                      const int*   __restrict__ receivers,
                      const ushort_t* __restrict__ w1t_hi,
                      const ushort_t* __restrict__ w1t_lo,
                      const ushort_t* __restrict__ w2t_hi,
                      const ushort_t* __restrict__ w2t_lo,
                      const float* __restrict__ b1,
                      const float* __restrict__ b2,
                      float*       agg,                 // [N_NODES*D] zeroed
                      float* __restrict__ edge_out)     // [N_EDGES*D]
{
    __shared__ uint4 lds16[4096];                       // 64 KiB, 16B aligned
    char* ldsb = (char*)lds16;
    __shared__ int sidx[TM];
    __shared__ int ridx[TM];

    const int tid  = threadIdx.x;
    const int lane = tid & 63;
    const int wid  = tid >> 6;
    const int e0   = blockIdx.x * TM;

    if (tid < TM) {
        int e = e0 + tid;
        sidx[tid] = (e < N_EDGES) ? senders[e]   : 0;
        ridx[tid] = (e < N_EDGES) ? receivers[e] : 0;
    }
    __syncthreads();

    // ---- stage: gather X = [node_latents[s], edge_latents] -> hi/lo bf16 ---
    // 64 rows x 32 chunks-of-8; thread handles 8 chunks.
    #pragma unroll
    for (int i = 0; i < 8; ++i) {
        int cf  = i * 256 + tid;
        int row = cf >> 5;
        int q   = cf & 31;                 // 8-elem chunk within 256-col row
        float v[8];
        bool live = (e0 + row < N_EDGES);
        if (q < 16) {
            const float4* p = reinterpret_cast<const float4*>(
                &node_latents[(size_t)sidx[row] * D + q * 8]);
            float4 a = p[0], b = p[1];
            v[0]=a.x; v[1]=a.y; v[2]=a.z; v[3]=a.w;
            v[4]=b.x; v[5]=b.y; v[6]=b.z; v[7]=b.w;
            if (!live) { v[0]=v[1]=v[2]=v[3]=v[4]=v[5]=v[6]=v[7]=0.f; }
        } else if (live) {
            size_t off = (size_t)(e0 + row) * D + (q - 16) * 8;
            const float4* p = reinterpret_cast<const float4*>(&edge_latents[off]);
            float4 a = p[0], b = p[1];
            v[0]=a.x; v[1]=a.y; v[2]=a.z; v[3]=a.w;
            v[4]=b.x; v[5]=b.y; v[6]=b.z; v[7]=b.w;
            float4* o = reinterpret_cast<float4*>(&edge_out[off]);
            o[0] = a; o[1] = b;            // fused pass-through
        } else {
            v[0]=v[1]=v[2]=v[3]=v[4]=v[5]=v[6]=v[7]=0.f;
        }
        ushort_t hi[8], lo[8];
        #pragma unroll
        for (int j = 0; j < 8; ++j) {
            hi[j] = f2bf(v[j]);
            lo[j] = f2bf(v[j] - bf2f(hi[j]));
        }
        int addr = (row * 512 + q * 16) ^ ((row & 7) << 4);
        *reinterpret_cast<s8v*>(ldsb + addr)         = *reinterpret_cast<s8v*>(hi);
        *reinterpret_cast<s8v*>(ldsb + 32768 + addr) = *reinterpret_cast<s8v*>(lo);
    }
    __syncthreads();

    // wave tile: wr in {0,1} -> rows wr*32..+31 ; wc in {0,1} -> cols wc*64..+63
    const int wr = wid >> 1;
    const int wc = wid & 1;
    const int l15 = lane & 15;
    const int kl  = lane >> 4;            // 0..3

    // ---- layer 1: H = relu(X @ W1 + b1), K=256 -----------------------------
    f4v acc[2][4];
    #pragma unroll
    for (int nt = 0; nt < 4; ++nt) {
        float bb = b1[wc * 64 + nt * 16 + l15];
        #pragma unroll
        for (int rt = 0; rt < 2; ++rt) acc[rt][nt] = f4v{bb, bb, bb, bb};
    }
    for (int kc = 0; kc < 8; ++kc) {
        s8v ahi[2], alo[2];
        #pragma unroll
        for (int rt = 0; rt < 2; ++rt) {
            int row  = wr * 32 + rt * 16 + l15;
            int addr = (row * 512 + kc * 64 + kl * 16) ^ ((row & 7) << 4);
            ahi[rt] = *reinterpret_cast<const s8v*>(ldsb + addr);
            alo[rt] = *reinterpret_cast<const s8v*>(ldsb + 32768 + addr);
        }
        #pragma unroll
        for (int nt = 0; nt < 4; ++nt) {
            int n   = wc * 64 + nt * 16 + l15;
            int off = n * 256 + kc * 32 + kl * 8;
            s8v bhi = *reinterpret_cast<const s8v*>(&w1t_hi[off]);
            s8v blo = *reinterpret_cast<const s8v*>(&w1t_lo[off]);
            #pragma unroll
            for (int rt = 0; rt < 2; ++rt) {
                acc[rt][nt] = __builtin_amdgcn_mfma_f32_16x16x32_bf16(ahi[rt], bhi, acc[rt][nt], 0, 0, 0);
                acc[rt][nt] = __builtin_amdgcn_mfma_f32_16x16x32_bf16(ahi[rt], blo, acc[rt][nt], 0, 0, 0);
                acc[rt][nt] = __builtin_amdgcn_mfma_f32_16x16x32_bf16(alo[rt], bhi, acc[rt][nt], 0, 0, 0);
            }
        }
    }
    __syncthreads();   // X fully consumed; reuse its LDS for H

    // ---- relu + hi/lo re-split of H into LDS (Hhi @0, Hlo @16384) ----------
    #pragma unroll
    for (int rt = 0; rt < 2; ++rt) {
        #pragma unroll
        for (int nt = 0; nt < 4; ++nt) {
            #pragma unroll
            for (int r = 0; r < 4; ++r) {
                int row = wr * 32 + rt * 16 + kl * 4 + r;
                int col = wc * 64 + nt * 16 + l15;
                float h = fmaxf(acc[rt][nt][r], 0.f);
                ushort_t hh = f2bf(h);
                ushort_t hl = f2bf(h - bf2f(hh));
                int addr = (row * 256 + col * 2) ^ ((row & 7) << 4);
                *reinterpret_cast<ushort_t*>(ldsb + addr)         = hh;
                *reinterpret_cast<ushort_t*>(ldsb + 16384 + addr) = hl;
            }
        }
    }
    __syncthreads();

    // ---- layer 2: M = H @ W2 + b2, K=128 -----------------------------------
    f4v acc2[2][4];
    #pragma unroll
    for (int nt = 0; nt < 4; ++nt) {
        float bb = b2[wc * 64 + nt * 16 + l15];
        #pragma unroll
        for (int rt = 0; rt < 2; ++rt) acc2[rt][nt] = f4v{bb, bb, bb, bb};
    }
    for (int kc = 0; kc < 4; ++kc) {
        s8v ahi[2], alo[2];
        #pragma unroll
        for (int rt = 0; rt < 2; ++rt) {
            int row  = wr * 32 + rt * 16 + l15;
            int addr = (row * 256 + kc * 64 + kl * 16) ^ ((row & 7) << 4);
            ahi[rt] = *reinterpret_cast<const s8v*>(ldsb + addr);
            alo[rt] = *reinterpret_cast<const s8v*>(ldsb + 16384 + addr);
        }
        #pragma unroll
        for (int nt = 0; nt < 4; ++nt) {
            int n   = wc * 64 + nt * 16 + l15;
            int off = n * 128 + kc * 32 + kl * 8;
            s8v bhi = *reinterpret_cast<const s8v*>(&w2t_hi[off]);
            s8v blo = *reinterpret_cast<const s8v*>(&w2t_lo[off]);
            #pragma unroll
            for (int rt = 0; rt < 2; ++rt) {
                acc2[rt][nt] = __builtin_amdgcn_mfma_f32_16x16x32_bf16(ahi[rt], bhi, acc2[rt][nt], 0, 0, 0);
                acc2[rt][nt] = __builtin_amdgcn_mfma_f32_16x16x32_bf16(ahi[rt], blo, acc2[rt][nt], 0, 0, 0);
                acc2[rt][nt] = __builtin_amdgcn_mfma_f32_16x16x32_bf16(alo[rt], bhi, acc2[rt][nt], 0, 0, 0);
            }
        }
    }

    // ---- scatter-add messages into aggregate -------------------------------
    #pragma unroll
    for (int rt = 0; rt < 2; ++rt) {
        #pragma unroll
        for (int r = 0; r < 4; ++r) {
            int row = wr * 32 + rt * 16 + kl * 4 + r;
            if (e0 + row < N_EDGES) {
                int rb = ridx[row] * D;
                #pragma unroll
                for (int nt = 0; nt < 4; ++nt) {
                    int col = wc * 64 + nt * 16 + l15;
                    atomicAdd(&agg[rb + col], acc2[rt][nt][r]);
                }
            }
        }
    }
}

// ---------------------------------------------------------------------------
// fp32 fallback edge kernel (used only if ws_size too small for weight prep).
// ---------------------------------------------------------------------------
__global__ __launch_bounds__(THREADS, 2)
void edge_kernel_fp32(const float* __restrict__ node_latents,
                      const float* __restrict__ edge_latents,
                      const int*   __restrict__ senders,
                      const int*   __restrict__ receivers,
                      const float* __restrict__ W1, const float* __restrict__ b1,
                      const float* __restrict__ W2, const float* __restrict__ b2,
                      float*       agg,
                      float* __restrict__ edge_out)
{
    __shared__ float smem[TM * TWO_D];
    __shared__ int   sidx[TM];
    __shared__ int   ridx[TM];

    const int tid = threadIdx.x;
    const int e0  = blockIdx.x * TM;

    if (tid < TM) {
        int e = e0 + tid;
        sidx[tid] = (e < N_EDGES) ? senders[e]   : 0;
        ridx[tid] = (e < N_EDGES) ? receivers[e] : 0;
    }
    __syncthreads();

    #pragma unroll
    for (int it = 0; it < (TM * TWO_D / 4) / THREADS; ++it) {
        int f = it * THREADS + tid;
        int e = f >> 6;
        int q = f & 63;
        float4 v;
        if (e0 + e < N_EDGES) {
            if (q < 32) {
                v = *reinterpret_cast<const float4*>(
                        &node_latents[(size_t)sidx[e] * D + q * 4]);
            } else {
                size_t off = (size_t)(e0 + e) * D + (q - 32) * 4;
                v = *reinterpret_cast<const float4*>(&edge_latents[off]);
                *reinterpret_cast<float4*>(&edge_out[off]) = v;
            }
        } else {
            v = make_float4(0.f, 0.f, 0.f, 0.f);
        }
        *reinterpret_cast<float4*>(&smem[e * TWO_D + q * 4]) = v;
    }
    __syncthreads();

    const int c  = tid & 63;
    const int eg = tid >> 6;

    float acc[16][2];
    {
        float bb0 = b1[c], bb1 = b1[c + 64];
        #pragma unroll
        for (int i = 0; i < 16; ++i) { acc[i][0] = bb0; acc[i][1] = bb1; }
    }
    for (int k = 0; k < TWO_D; k += 4) {
        float wa[4], wb[4];
        #pragma unroll
        for (int j = 0; j < 4; ++j) {
            wa[j] = W1[(k + j) * D + c];
            wb[j] = W1[(k + j) * D + c + 64];
        }
        #pragma unroll
        for (int i = 0; i < 16; ++i) {
            const float4 xv = *reinterpret_cast<const float4*>(
                                  &smem[(eg * 16 + i) * TWO_D + k]);
            acc[i][0] = fmaf(xv.x, wa[0], acc[i][0]);
            acc[i][1] = fmaf(xv.x, wb[0], acc[i][1]);
            acc[i][0] = fmaf(xv.y, wa[1], acc[i][0]);
            acc[i][1] = fmaf(xv.y, wb[1], acc[i][1]);
            acc[i][0] = fmaf(xv.z, wa[2], acc[i][0]);
            acc[i][1] = fmaf(xv.z, wb[2], acc[i][1]);
            acc[i][0] = fmaf(xv.w, wa[3], acc[i][0]);
            acc[i][1] = fmaf(xv.w, wb[3], acc[i][1]);
        }
    }
    __syncthreads();

    #pragma unroll
    for (int i = 0; i < 16; ++i) {
        int e = eg * 16 + i;
        smem[e * D + c]      = fmaxf(acc[i][0], 0.f);
        smem[e * D + c + 64] = fmaxf(acc[i][1], 0.f);
    }
    __syncthreads();

    float acc2[16][2];
    {
        float bb0 = b2[c], bb1 = b2[c + 64];
        #pragma unroll
        for (int i = 0; i < 16; ++i) { acc2[i][0] = bb0; acc2[i][1] = bb1; }
    }
    for (int k = 0; k < D; k += 4) {
        float wa[4], wb[4];
        #pragma unroll
        for (int j = 0; j < 4; ++j) {
            wa[j] = W2[(k + j) * D + c];
            wb[j] = W2[(k + j) * D + c + 64];
        }
        #pragma unroll
        for (int i = 0; i < 16; ++i) {
            const float4 hv = *reinterpret_cast<const float4*>(
                                  &smem[(eg * 16 + i) * D + k]);
            acc2[i][0] = fmaf(hv.x, wa[0], acc2[i][0]);
            acc2[i][1] = fmaf(hv.x, wb[0], acc2[i][1]);
            acc2[i][0] = fmaf(hv.y, wa[1], acc2[i][0]);
            acc2[i][1] = fmaf(hv.y, wb[1], acc2[i][1]);
            acc2[i][0] = fmaf(hv.z, wa[2], acc2[i][0]);
            acc2[i][1] = fmaf(hv.z, wb[2], acc2[i][1]);
            acc2[i][0] = fmaf(hv.w, wa[3], acc2[i][0]);
            acc2[i][1] = fmaf(hv.w, wb[3], acc2[i][1]);
        }
    }

    #pragma unroll
    for (int i = 0; i < 16; ++i) {
        int el = eg * 16 + i;
        if (e0 + el < N_EDGES) {
            int r = ridx[el];
            atomicAdd(&agg[(size_t)r * D + c],      acc2[i][0]);
            atomicAdd(&agg[(size_t)r * D + c + 64], acc2[i][1]);
        }
    }
}

// ---------------------------------------------------------------------------
// Node kernel (fp32 VALU): out = relu([node, agg] @ U1 + ub1) @ U2 + ub2.
// agg aliases node_out; reads barrier-separated from writes, rows disjoint.
// ---------------------------------------------------------------------------
__global__ __launch_bounds__(THREADS, 2)
void node_kernel(const float* __restrict__ node_latents,
                 const float* agg,
                 const float* __restrict__ U1, const float* __restrict__ ub1,
                 const float* __restrict__ U2, const float* __restrict__ ub2,
                 float*       node_out)
{
    __shared__ float smem[TM * TWO_D];

    const int tid = threadIdx.x;
    const int n0  = blockIdx.x * TM;

    #pragma unroll
    for (int it = 0; it < (TM * TWO_D / 4) / THREADS; ++it) {
        int f = it * THREADS + tid;
        int e = f >> 6;
        int q = f & 63;
        float4 v;
        if (n0 + e < N_NODES) {
            if (q < 32) {
                v = *reinterpret_cast<const float4*>(
                        &node_latents[(size_t)(n0 + e) * D + q * 4]);
            } else {
                v = *reinterpret_cast<const float4*>(
                        &agg[(size_t)(n0 + e) * D + (q - 32) * 4]);
            }
        } else {
            v = make_float4(0.f, 0.f, 0.f, 0.f);
        }
        *reinterpret_cast<float4*>(&smem[e * TWO_D + q * 4]) = v;
    }
    __syncthreads();

    const int c  = tid & 63;
    const int eg = tid >> 6;

    float acc[16][2];
    {
        float bb0 = ub1[c], bb1 = ub1[c + 64];
        #pragma unroll
        for (int i = 0; i < 16; ++i) { acc[i][0] = bb0; acc[i][1] = bb1; }
    }
    for (int k = 0; k < TWO_D; k += 4) {
        float wa[4], wb[4];
        #pragma unroll
        for (int j = 0; j < 4; ++j) {
            wa[j] = U1[(k + j) * D + c];
            wb[j] = U1[(k + j) * D + c + 64];
        }
        #pragma unroll
        for (int i = 0; i < 16; ++i) {
            const float4 xv = *reinterpret_cast<const float4*>(
                                  &smem[(eg * 16 + i) * TWO_D + k]);
            acc[i][0] = fmaf(xv.x, wa[0], acc[i][0]);
            acc[i][1] = fmaf(xv.x, wb[0], acc[i][1]);
            acc[i][0] = fmaf(xv.y, wa[1], acc[i][0]);
            acc[i][1] = fmaf(xv.y, wb[1], acc[i][1]);
            acc[i][0] = fmaf(xv.z, wa[2], acc[i][0]);
            acc[i][1] = fmaf(xv.z, wb[2], acc[i][1]);
            acc[i][0] = fmaf(xv.w, wa[3], acc[i][0]);
            acc[i][1] = fmaf(xv.w, wb[3], acc[i][1]);
        }
    }
    __syncthreads();

    #pragma unroll
    for (int i = 0; i < 16; ++i) {
        int e = eg * 16 + i;
        smem[e * D + c]      = fmaxf(acc[i][0], 0.f);
        smem[e * D + c + 64] = fmaxf(acc[i][1], 0.f);
    }
    __syncthreads();

    float acc2[16][2];
    {
        float bb0 = ub2[c], bb1 = ub2[c + 64];
        #pragma unroll
        for (int i = 0; i < 16; ++i) { acc2[i][0] = bb0; acc2[i][1] = bb1; }
    }
    for (int k = 0; k < D; k += 4) {
        float wa[4], wb[4];
        #pragma unroll
        for (int j = 0; j < 4; ++j) {
            wa[j] = U2[(k + j) * D + c];
            wb[j] = U2[(k + j) * D + c + 64];
        }
        #pragma unroll
        for (int i = 0; i < 16; ++i) {
            const float4 hv = *reinterpret_cast<const float4*>(
                                  &smem[(eg * 16 + i) * D + k]);
            acc2[i][0] = fmaf(hv.x, wa[0], acc2[i][0]);
            acc2[i][1] = fmaf(hv.x, wb[0], acc2[i][1]);
            acc2[i][0] = fmaf(hv.y, wa[1], acc2[i][0]);
            acc2[i][1] = fmaf(hv.y, wb[1], acc2[i][1]);
            acc2[i][0] = fmaf(hv.z, wa[2], acc2[i][0]);
            acc2[i][1] = fmaf(hv.z, wb[2], acc2[i][1]);
            acc2[i][0] = fmaf(hv.w, wa[3], acc2[i][0]);
            acc2[i][1] = fmaf(hv.w, wb[3], acc2[i][1]);
        }
    }

    #pragma unroll
    for (int i = 0; i < 16; ++i) {
        int n = n0 + eg * 16 + i;
        if (n < N_NODES) {
            node_out[(size_t)n * D + c]      = acc2[i][0];
            node_out[(size_t)n * D + c + 64] = acc2[i][1];
        }
    }
}

extern "C" void kernel_launch(void* const* d_in, const int* in_sizes, int n_in,
                              void* d_out, int out_size, void* d_ws, size_t ws_size,
                              hipStream_t stream) {
    const float* node_latents = (const float*)d_in[0];
    const float* edge_latents = (const float*)d_in[1];
    const int*   edge_index   = (const int*)  d_in[2];
    const float* W1  = (const float*)d_in[3];
    const float* b1  = (const float*)d_in[4];
    const float* W2  = (const float*)d_in[5];
    const float* b2  = (const float*)d_in[6];
    const float* U1  = (const float*)d_in[7];
    const float* ub1 = (const float*)d_in[8];
    const float* U2  = (const float*)d_in[9];
    const float* ub2 = (const float*)d_in[10];

    float* out      = (float*)d_out;
    float* node_out = out;                               // [N*D]
    float* edge_out = out + (size_t)N_NODES * D;         // [E*D]
    const int* senders   = edge_index;
    const int* receivers = edge_index + N_EDGES;

    // node_out doubles as the segment-sum accumulator; zero it.
    hipMemsetAsync(node_out, 0, (size_t)N_NODES * D * sizeof(float), stream);

    dim3 blk(THREADS);
    dim3 ge((N_EDGES + TM - 1) / TM);
    dim3 gn((N_NODES + TM - 1) / TM);

    // ws layout: w1t_hi[32768] | w1t_lo[32768] | w2t_hi[16384] | w2t_lo[16384]
    const size_t WS_NEED = (size_t)(32768 + 32768 + 16384 + 16384) * sizeof(ushort_t);
    if (ws_size >= WS_NEED) {
        ushort_t* w1t_hi = (ushort_t*)d_ws;
        ushort_t* w1t_lo = w1t_hi + 32768;
        ushort_t* w2t_hi = w1t_lo + 32768;
        ushort_t* w2t_lo = w2t_hi + 16384;
        prep_weights<<<dim3(192), blk, 0, stream>>>(W1, W2, w1t_hi, w1t_lo, w2t_hi, w2t_lo);
        edge_kernel_mfma<<<ge, blk, 0, stream>>>(node_latents, edge_latents,
                                                 senders, receivers,
                                                 w1t_hi, w1t_lo, w2t_hi, w2t_lo,
                                                 b1, b2,
                                                 node_out /*agg*/, edge_out);
    } else {
        edge_kernel_fp32<<<ge, blk, 0, stream>>>(node_latents, edge_latents,
                                                 senders, receivers,
                                                 W1, b1, W2, b2,
                                                 node_out /*agg*/, edge_out);
    }

    node_kernel<<<gn, blk, 0, stream>>>(node_latents, node_out /*agg*/,
                                        U1, ub1, U2, ub2, node_out);
}

// Round 3
// 898.206 us; speedup vs baseline: 1.3952x; 1.3952x over previous
//
#include <hip/hip_runtime.h>

#define N_NODES 50000
#define N_EDGES 625000
#define D       128
#define TWO_D   256
#define TM      64

typedef short  s8v  __attribute__((ext_vector_type(8)));   // 8 bf16 (4 VGPRs)
typedef float  f4v  __attribute__((ext_vector_type(4)));   // 4 f32 acc
typedef unsigned short ushort_t;
typedef unsigned int   uint_t;

// ---- fp32 <-> bf16 (RNE) helpers ------------------------------------------
static __device__ __forceinline__ ushort_t f2bf(float f) {
    uint_t u = __builtin_bit_cast(uint_t, f);
    u = (u + 0x7FFFu + ((u >> 16) & 1u)) >> 16;
    return (ushort_t)u;
}
static __device__ __forceinline__ float bf2f(ushort_t h) {
    uint_t u = ((uint_t)h) << 16;
    return __builtin_bit_cast(float, u);
}

// ---------------------------------------------------------------------------
// Weight prep: hi/lo split + MFMA-FRAGMENT-PACKED layout.
// For W [Kd x 128] row-major: out[(n16*(Kd/32) + kc)*512 + (kl*16+l15)*8 + j]
//   where n = n16*16+l15 (output col), k = kc*32 + kl*8 + j.
// A wave load of one fragment = 64 lanes x 16B CONTIGUOUS (4 cache lines).
// ---------------------------------------------------------------------------
__global__ void prep_weights(const float* __restrict__ W1,
                             const float* __restrict__ W2,
                             const float* __restrict__ U1,
                             const float* __restrict__ U2,
                             ushort_t* __restrict__ w1f_hi, ushort_t* __restrict__ w1f_lo,
                             ushort_t* __restrict__ w2f_hi, ushort_t* __restrict__ w2f_lo,
                             ushort_t* __restrict__ u1f_hi, ushort_t* __restrict__ u1f_lo,
                             ushort_t* __restrict__ u2f_hi, ushort_t* __restrict__ u2f_lo)
{
    int t = blockIdx.x * 256 + threadIdx.x;
    const float* src; ushort_t* dhi; ushort_t* dlo; int Kd; int id;
    if (t < 32768)        { src = W1; dhi = w1f_hi; dlo = w1f_lo; Kd = 256; id = t; }
    else if (t < 49152)   { src = W2; dhi = w2f_hi; dlo = w2f_lo; Kd = 128; id = t - 32768; }
    else if (t < 81920)   { src = U1; dhi = u1f_hi; dlo = u1f_lo; Kd = 256; id = t - 49152; }
    else if (t < 98304)   { src = U2; dhi = u2f_hi; dlo = u2f_lo; Kd = 128; id = t - 81920; }
    else return;

    int n = id / Kd;
    int k = id % Kd;
    float w = src[k * D + n];
    ushort_t h = f2bf(w);
    ushort_t l = f2bf(w - bf2f(h));
    int n16 = n >> 4, l15 = n & 15;
    int kc = k >> 5, kl = (k & 31) >> 3, j = k & 7;
    int flat = (n16 * (Kd >> 5) + kc) * 512 + (kl * 16 + l15) * 8 + j;
    dhi[flat] = h;
    dlo[flat] = l;
}

// ---------------------------------------------------------------------------
// MFMA edge kernel. 512 thr = 8 waves (2 row x 4 col). 64 edges/block.
// LDS 64KB: Xhi@0 [64][256]bf16, Xlo@32768; after layer1: Hhi@0, Hlo@16384.
// Swizzle byte ^= (row&7)<<4 on all LDS accesses.
// ---------------------------------------------------------------------------
__global__ __launch_bounds__(512, 4)
void edge_kernel_mfma(const float* __restrict__ node_latents,
                      const float* __restrict__ edge_latents,
                      const int*   __restrict__ senders,
                      const int*   __restrict__ receivers,
                      const ushort_t* __restrict__ w1f_hi, const ushort_t* __restrict__ w1f_lo,
                      const ushort_t* __restrict__ w2f_hi, const ushort_t* __restrict__ w2f_lo,
                      const float* __restrict__ b1, const float* __restrict__ b2,
                      float*       agg,
                      float* __restrict__ edge_out)
{
    __shared__ uint4 lds16[4096];          // 64 KiB
    char* ldsb = (char*)lds16;
    __shared__ int sidx[TM];
    __shared__ int ridx[TM];

    const int tid  = threadIdx.x;
    const int lane = tid & 63;
    const int wid  = tid >> 6;             // 0..7
    const int e0   = blockIdx.x * TM;

    if (tid < TM) {
        int e = e0 + tid;
        sidx[tid] = (e < N_EDGES) ? senders[e]   : 0;
        ridx[tid] = (e < N_EDGES) ? receivers[e] : 0;
    }
    __syncthreads();

    // ---- stage X = [gather(node_latents), edge_latents] -> hi/lo bf16 ------
    #pragma unroll
    for (int i = 0; i < 4; ++i) {
        int cf  = i * 512 + tid;           // 0..2047
        int row = cf >> 5;
        int q   = cf & 31;
        float v[8];
        bool live = (e0 + row < N_EDGES);
        if (q < 16) {
            const float4* p = reinterpret_cast<const float4*>(
                &node_latents[(size_t)sidx[row] * D + q * 8]);
            float4 a = p[0], b = p[1];
            v[0]=a.x; v[1]=a.y; v[2]=a.z; v[3]=a.w;
            v[4]=b.x; v[5]=b.y; v[6]=b.z; v[7]=b.w;
            if (!live) { v[0]=v[1]=v[2]=v[3]=v[4]=v[5]=v[6]=v[7]=0.f; }
        } else if (live) {
            size_t off = (size_t)(e0 + row) * D + (q - 16) * 8;
            const float4* p = reinterpret_cast<const float4*>(&edge_latents[off]);
            float4 a = p[0], b = p[1];
            v[0]=a.x; v[1]=a.y; v[2]=a.z; v[3]=a.w;
            v[4]=b.x; v[5]=b.y; v[6]=b.z; v[7]=b.w;
            float4* o = reinterpret_cast<float4*>(&edge_out[off]);
            o[0] = a; o[1] = b;            // fused pass-through
        } else {
            v[0]=v[1]=v[2]=v[3]=v[4]=v[5]=v[6]=v[7]=0.f;
        }
        ushort_t hi[8], lo[8];
        #pragma unroll
        for (int j = 0; j < 8; ++j) {
            hi[j] = f2bf(v[j]);
            lo[j] = f2bf(v[j] - bf2f(hi[j]));
        }
        int addr = (row * 512 + q * 16) ^ ((row & 7) << 4);
        *reinterpret_cast<s8v*>(ldsb + addr)         = *reinterpret_cast<s8v*>(hi);
        *reinterpret_cast<s8v*>(ldsb + 32768 + addr) = *reinterpret_cast<s8v*>(lo);
    }
    __syncthreads();

    const int wr  = wid >> 2;              // 0..1 : rows wr*32..+31
    const int wc  = wid & 3;               // 0..3 : cols wc*32..+31
    const int l15 = lane & 15;
    const int kl  = lane >> 4;

    // ---- layer 1: H = relu(X @ W1 + b1), K=256 -----------------------------
    f4v acc[2][2];
    #pragma unroll
    for (int nt = 0; nt < 2; ++nt) {
        float bb = b1[wc * 32 + nt * 16 + l15];
        acc[0][nt] = f4v{bb, bb, bb, bb};
        acc[1][nt] = f4v{bb, bb, bb, bb};
    }
    for (int kc = 0; kc < 8; ++kc) {
        s8v ahi[2], alo[2];
        #pragma unroll
        for (int rt = 0; rt < 2; ++rt) {
            int row  = wr * 32 + rt * 16 + l15;
            int addr = (row * 512 + kc * 64 + kl * 16) ^ ((row & 7) << 4);
            ahi[rt] = *reinterpret_cast<const s8v*>(ldsb + addr);
            alo[rt] = *reinterpret_cast<const s8v*>(ldsb + 32768 + addr);
        }
        #pragma unroll
        for (int nt = 0; nt < 2; ++nt) {
            int frag = ((wc * 2 + nt) * 8 + kc) * 512 + lane * 8;
            s8v bhi = *reinterpret_cast<const s8v*>(&w1f_hi[frag]);
            s8v blo = *reinterpret_cast<const s8v*>(&w1f_lo[frag]);
            #pragma unroll
            for (int rt = 0; rt < 2; ++rt) {
                acc[rt][nt] = __builtin_amdgcn_mfma_f32_16x16x32_bf16(ahi[rt], bhi, acc[rt][nt], 0, 0, 0);
                acc[rt][nt] = __builtin_amdgcn_mfma_f32_16x16x32_bf16(ahi[rt], blo, acc[rt][nt], 0, 0, 0);
                acc[rt][nt] = __builtin_amdgcn_mfma_f32_16x16x32_bf16(alo[rt], bhi, acc[rt][nt], 0, 0, 0);
            }
        }
    }
    __syncthreads();   // X consumed; reuse for H

    // ---- relu + hi/lo re-split of H (Hhi@0, Hlo@16384) ---------------------
    #pragma unroll
    for (int rt = 0; rt < 2; ++rt) {
        #pragma unroll
        for (int nt = 0; nt < 2; ++nt) {
            #pragma unroll
            for (int r = 0; r < 4; ++r) {
                int row = wr * 32 + rt * 16 + kl * 4 + r;
                int col = wc * 32 + nt * 16 + l15;
                float h = fmaxf(acc[rt][nt][r], 0.f);
                ushort_t hh = f2bf(h);
                ushort_t hl = f2bf(h - bf2f(hh));
                int addr = (row * 256 + col * 2) ^ ((row & 7) << 4);
                *reinterpret_cast<ushort_t*>(ldsb + addr)         = hh;
                *reinterpret_cast<ushort_t*>(ldsb + 16384 + addr) = hl;
            }
        }
    }
    __syncthreads();

    // ---- layer 2: M = H @ W2 + b2, K=128 -----------------------------------
    f4v acc2[2][2];
    #pragma unroll
    for (int nt = 0; nt < 2; ++nt) {
        float bb = b2[wc * 32 + nt * 16 + l15];
        acc2[0][nt] = f4v{bb, bb, bb, bb};
        acc2[1][nt] = f4v{bb, bb, bb, bb};
    }
    for (int kc = 0; kc < 4; ++kc) {
        s8v ahi[2], alo[2];
        #pragma unroll
        for (int rt = 0; rt < 2; ++rt) {
            int row  = wr * 32 + rt * 16 + l15;
            int addr = (row * 256 + kc * 64 + kl * 16) ^ ((row & 7) << 4);
            ahi[rt] = *reinterpret_cast<const s8v*>(ldsb + addr);
            alo[rt] = *reinterpret_cast<const s8v*>(ldsb + 16384 + addr);
        }
        #pragma unroll
        for (int nt = 0; nt < 2; ++nt) {
            int frag = ((wc * 2 + nt) * 4 + kc) * 512 + lane * 8;
            s8v bhi = *reinterpret_cast<const s8v*>(&w2f_hi[frag]);
            s8v blo = *reinterpret_cast<const s8v*>(&w2f_lo[frag]);
            #pragma unroll
            for (int rt = 0; rt < 2; ++rt) {
                acc2[rt][nt] = __builtin_amdgcn_mfma_f32_16x16x32_bf16(ahi[rt], bhi, acc2[rt][nt], 0, 0, 0);
                acc2[rt][nt] = __builtin_amdgcn_mfma_f32_16x16x32_bf16(ahi[rt], blo, acc2[rt][nt], 0, 0, 0);
                acc2[rt][nt] = __builtin_amdgcn_mfma_f32_16x16x32_bf16(alo[rt], bhi, acc2[rt][nt], 0, 0, 0);
            }
        }
    }

    // ---- scatter-add ------------------------------------------------------
    #pragma unroll
    for (int rt = 0; rt < 2; ++rt) {
        #pragma unroll
        for (int r = 0; r < 4; ++r) {
            int row = wr * 32 + rt * 16 + kl * 4 + r;
            if (e0 + row < N_EDGES) {
                int rb = ridx[row] * D;
                #pragma unroll
                for (int nt = 0; nt < 2; ++nt) {
                    int col = wc * 32 + nt * 16 + l15;
                    atomicAdd(&agg[rb + col], acc2[rt][nt][r]);
                }
            }
        }
    }
}

// ---------------------------------------------------------------------------
// MFMA node kernel: out = relu([node, agg] @ U1 + ub1) @ U2 + ub2.
// Same structure, linear loads, direct stores. agg aliases node_out (rows
// disjoint per block, reads barrier-separated from writes).
// ---------------------------------------------------------------------------
__global__ __launch_bounds__(512, 4)
void node_kernel_mfma(const float* __restrict__ node_latents,
                      const float* agg,
                      const ushort_t* __restrict__ u1f_hi, const ushort_t* __restrict__ u1f_lo,
                      const ushort_t* __restrict__ u2f_hi, const ushort_t* __restrict__ u2f_lo,
                      const float* __restrict__ ub1, const float* __restrict__ ub2,
                      float*       node_out)
{
    __shared__ uint4 lds16[4096];
    char* ldsb = (char*)lds16;

    const int tid  = threadIdx.x;
    const int lane = tid & 63;
    const int wid  = tid >> 6;
    const int n0   = blockIdx.x * TM;

    #pragma unroll
    for (int i = 0; i < 4; ++i) {
        int cf  = i * 512 + tid;
        int row = cf >> 5;
        int q   = cf & 31;
        float v[8];
        bool live = (n0 + row < N_NODES);
        if (live) {
            size_t base = (size_t)(n0 + row) * D;
            const float4* p = (q < 16)
                ? reinterpret_cast<const float4*>(&node_latents[base + q * 8])
                : reinterpret_cast<const float4*>(&agg[base + (q - 16) * 8]);
            float4 a = p[0], b = p[1];
            v[0]=a.x; v[1]=a.y; v[2]=a.z; v[3]=a.w;
            v[4]=b.x; v[5]=b.y; v[6]=b.z; v[7]=b.w;
        } else {
            v[0]=v[1]=v[2]=v[3]=v[4]=v[5]=v[6]=v[7]=0.f;
        }
        ushort_t hi[8], lo[8];
        #pragma unroll
        for (int j = 0; j < 8; ++j) {
            hi[j] = f2bf(v[j]);
            lo[j] = f2bf(v[j] - bf2f(hi[j]));
        }
        int addr = (row * 512 + q * 16) ^ ((row & 7) << 4);
        *reinterpret_cast<s8v*>(ldsb + addr)         = *reinterpret_cast<s8v*>(hi);
        *reinterpret_cast<s8v*>(ldsb + 32768 + addr) = *reinterpret_cast<s8v*>(lo);
    }
    __syncthreads();

    const int wr  = wid >> 2;
    const int wc  = wid & 3;
    const int l15 = lane & 15;
    const int kl  = lane >> 4;

    f4v acc[2][2];
    #pragma unroll
    for (int nt = 0; nt < 2; ++nt) {
        float bb = ub1[wc * 32 + nt * 16 + l15];
        acc[0][nt] = f4v{bb, bb, bb, bb};
        acc[1][nt] = f4v{bb, bb, bb, bb};
    }
    for (int kc = 0; kc < 8; ++kc) {
        s8v ahi[2], alo[2];
        #pragma unroll
        for (int rt = 0; rt < 2; ++rt) {
            int row  = wr * 32 + rt * 16 + l15;
            int addr = (row * 512 + kc * 64 + kl * 16) ^ ((row & 7) << 4);
            ahi[rt] = *reinterpret_cast<const s8v*>(ldsb + addr);
            alo[rt] = *reinterpret_cast<const s8v*>(ldsb + 32768 + addr);
        }
        #pragma unroll
        for (int nt = 0; nt < 2; ++nt) {
            int frag = ((wc * 2 + nt) * 8 + kc) * 512 + lane * 8;
            s8v bhi = *reinterpret_cast<const s8v*>(&u1f_hi[frag]);
            s8v blo = *reinterpret_cast<const s8v*>(&u1f_lo[frag]);
            #pragma unroll
            for (int rt = 0; rt < 2; ++rt) {
                acc[rt][nt] = __builtin_amdgcn_mfma_f32_16x16x32_bf16(ahi[rt], bhi, acc[rt][nt], 0, 0, 0);
                acc[rt][nt] = __builtin_amdgcn_mfma_f32_16x16x32_bf16(ahi[rt], blo, acc[rt][nt], 0, 0, 0);
                acc[rt][nt] = __builtin_amdgcn_mfma_f32_16x16x32_bf16(alo[rt], bhi, acc[rt][nt], 0, 0, 0);
            }
        }
    }
    __syncthreads();

    #pragma unroll
    for (int rt = 0; rt < 2; ++rt) {
        #pragma unroll
        for (int nt = 0; nt < 2; ++nt) {
            #pragma unroll
            for (int r = 0; r < 4; ++r) {
                int row = wr * 32 + rt * 16 + kl * 4 + r;
                int col = wc * 32 + nt * 16 + l15;
                float h = fmaxf(acc[rt][nt][r], 0.f);
                ushort_t hh = f2bf(h);
                ushort_t hl = f2bf(h - bf2f(hh));
                int addr = (row * 256 + col * 2) ^ ((row & 7) << 4);
                *reinterpret_cast<ushort_t*>(ldsb + addr)         = hh;
                *reinterpret_cast<ushort_t*>(ldsb + 16384 + addr) = hl;
            }
        }
    }
    __syncthreads();

    f4v acc2[2][2];
    #pragma unroll
    for (int nt = 0; nt < 2; ++nt) {
        float bb = ub2[wc * 32 + nt * 16 + l15];
        acc2[0][nt] = f4v{bb, bb, bb, bb};
        acc2[1][nt] = f4v{bb, bb, bb, bb};
    }
    for (int kc = 0; kc < 4; ++kc) {
        s8v ahi[2], alo[2];
        #pragma unroll
        for (int rt = 0; rt < 2; ++rt) {
            int row  = wr * 32 + rt * 16 + l15;
            int addr = (row * 256 + kc * 64 + kl * 16) ^ ((row & 7) << 4);
            ahi[rt] = *reinterpret_cast<const s8v*>(ldsb + addr);
            alo[rt] = *reinterpret_cast<const s8v*>(ldsb + 16384 + addr);
        }
        #pragma unroll
        for (int nt = 0; nt < 2; ++nt) {
            int frag = ((wc * 2 + nt) * 4 + kc) * 512 + lane * 8;
            s8v bhi = *reinterpret_cast<const s8v*>(&u2f_hi[frag]);
            s8v blo = *reinterpret_cast<const s8v*>(&u2f_lo[frag]);
            #pragma unroll
            for (int rt = 0; rt < 2; ++rt) {
                acc2[rt][nt] = __builtin_amdgcn_mfma_f32_16x16x32_bf16(ahi[rt], bhi, acc2[rt][nt], 0, 0, 0);
                acc2[rt][nt] = __builtin_amdgcn_mfma_f32_16x16x32_bf16(ahi[rt], blo, acc2[rt][nt], 0, 0, 0);
                acc2[rt][nt] = __builtin_amdgcn_mfma_f32_16x16x32_bf16(alo[rt], bhi, acc2[rt][nt], 0, 0, 0);
            }
        }
    }

    #pragma unroll
    for (int rt = 0; rt < 2; ++rt) {
        #pragma unroll
        for (int r = 0; r < 4; ++r) {
            int row = wr * 32 + rt * 16 + kl * 4 + r;
            int n   = n0 + row;
            if (n < N_NODES) {
                #pragma unroll
                for (int nt = 0; nt < 2; ++nt) {
                    int col = wc * 32 + nt * 16 + l15;
                    node_out[(size_t)n * D + col] = acc2[rt][nt][r];
                }
            }
        }
    }
}

// ---------------------------------------------------------------------------
// fp32 fallback kernels (only if ws_size is too small) — 256 threads.
// ---------------------------------------------------------------------------
__global__ __launch_bounds__(256, 2)
void edge_kernel_fp32(const float* __restrict__ node_latents,
                      const float* __restrict__ edge_latents,
                      const int*   __restrict__ senders,
                      const int*   __restrict__ receivers,
                      const float* __restrict__ W1, const float* __restrict__ b1,
                      const float* __restrict__ W2, const float* __restrict__ b2,
                      float*       agg,
                      float* __restrict__ edge_out)
{
    __shared__ float smem[TM * TWO_D];
    __shared__ int   sidx[TM];
    __shared__ int   ridx[TM];
    const int tid = threadIdx.x;
    const int e0  = blockIdx.x * TM;
    if (tid < TM) {
        int e = e0 + tid;
        sidx[tid] = (e < N_EDGES) ? senders[e]   : 0;
        ridx[tid] = (e < N_EDGES) ? receivers[e] : 0;
    }
    __syncthreads();
    #pragma unroll
    for (int it = 0; it < 16; ++it) {
        int f = it * 256 + tid;
        int e = f >> 6;
        int q = f & 63;
        float4 v;
        if (e0 + e < N_EDGES) {
            if (q < 32) {
                v = *reinterpret_cast<const float4*>(&node_latents[(size_t)sidx[e] * D + q * 4]);
            } else {
                size_t off = (size_t)(e0 + e) * D + (q - 32) * 4;
                v = *reinterpret_cast<const float4*>(&edge_latents[off]);
                *reinterpret_cast<float4*>(&edge_out[off]) = v;
            }
        } else v = make_float4(0.f, 0.f, 0.f, 0.f);
        *reinterpret_cast<float4*>(&smem[e * TWO_D + q * 4]) = v;
    }
    __syncthreads();
    const int c  = tid & 63;
    const int eg = tid >> 6;
    float acc[16][2];
    { float b0 = b1[c], bb = b1[c + 64];
      #pragma unroll
      for (int i = 0; i < 16; ++i) { acc[i][0] = b0; acc[i][1] = bb; } }
    for (int k = 0; k < TWO_D; k += 4) {
        float wa[4], wb[4];
        #pragma unroll
        for (int j = 0; j < 4; ++j) { wa[j] = W1[(k + j) * D + c]; wb[j] = W1[(k + j) * D + c + 64]; }
        #pragma unroll
        for (int i = 0; i < 16; ++i) {
            const float4 xv = *reinterpret_cast<const float4*>(&smem[(eg * 16 + i) * TWO_D + k]);
            acc[i][0] = fmaf(xv.x, wa[0], acc[i][0]); acc[i][1] = fmaf(xv.x, wb[0], acc[i][1]);
            acc[i][0] = fmaf(xv.y, wa[1], acc[i][0]); acc[i][1] = fmaf(xv.y, wb[1], acc[i][1]);
            acc[i][0] = fmaf(xv.z, wa[2], acc[i][0]); acc[i][1] = fmaf(xv.z, wb[2], acc[i][1]);
            acc[i][0] = fmaf(xv.w, wa[3], acc[i][0]); acc[i][1] = fmaf(xv.w, wb[3], acc[i][1]);
        }
    }
    __syncthreads();
    #pragma unroll
    for (int i = 0; i < 16; ++i) {
        int e = eg * 16 + i;
        smem[e * D + c] = fmaxf(acc[i][0], 0.f);
        smem[e * D + c + 64] = fmaxf(acc[i][1], 0.f);
    }
    __syncthreads();
    float acc2[16][2];
    { float b0 = b2[c], bb = b2[c + 64];
      #pragma unroll
      for (int i = 0; i < 16; ++i) { acc2[i][0] = b0; acc2[i][1] = bb; } }
    for (int k = 0; k < D; k += 4) {
        float wa[4], wb[4];
        #pragma unroll
        for (int j = 0; j < 4; ++j) { wa[j] = W2[(k + j) * D + c]; wb[j] = W2[(k + j) * D + c + 64]; }
        #pragma unroll
        for (int i = 0; i < 16; ++i) {
            const float4 hv = *reinterpret_cast<const float4*>(&smem[(eg * 16 + i) * D + k]);
            acc2[i][0] = fmaf(hv.x, wa[0], acc2[i][0]); acc2[i][1] = fmaf(hv.x, wb[0], acc2[i][1]);
            acc2[i][0] = fmaf(hv.y, wa[1], acc2[i][0]); acc2[i][1] = fmaf(hv.y, wb[1], acc2[i][1]);
            acc2[i][0] = fmaf(hv.z, wa[2], acc2[i][0]); acc2[i][1] = fmaf(hv.z, wb[2], acc2[i][1]);
            acc2[i][0] = fmaf(hv.w, wa[3], acc2[i][0]); acc2[i][1] = fmaf(hv.w, wb[3], acc2[i][1]);
        }
    }
    #pragma unroll
    for (int i = 0; i < 16; ++i) {
        int el = eg * 16 + i;
        if (e0 + el < N_EDGES) {
            int r = ridx[el];
            atomicAdd(&agg[(size_t)r * D + c],      acc2[i][0]);
            atomicAdd(&agg[(size_t)r * D + c + 64], acc2[i][1]);
        }
    }
}

__global__ __launch_bounds__(256, 2)
void node_kernel_fp32(const float* __restrict__ node_latents,
                      const float* agg,
                      const float* __restrict__ U1, const float* __restrict__ ub1,
                      const float* __restrict__ U2, const float* __restrict__ ub2,
                      float*       node_out)
{
    __shared__ float smem[TM * TWO_D];
    const int tid = threadIdx.x;
    const int n0  = blockIdx.x * TM;
    #pragma unroll
    for (int it = 0; it < 16; ++it) {
        int f = it * 256 + tid;
        int e = f >> 6;
        int q = f & 63;
        float4 v;
        if (n0 + e < N_NODES) {
            v = (q < 32)
              ? *reinterpret_cast<const float4*>(&node_latents[(size_t)(n0 + e) * D + q * 4])
              : *reinterpret_cast<const float4*>(&agg[(size_t)(n0 + e) * D + (q - 32) * 4]);
        } else v = make_float4(0.f, 0.f, 0.f, 0.f);
        *reinterpret_cast<float4*>(&smem[e * TWO_D + q * 4]) = v;
    }
    __syncthreads();
    const int c  = tid & 63;
    const int eg = tid >> 6;
    float acc[16][2];
    { float b0 = ub1[c], bb = ub1[c + 64];
      #pragma unroll
      for (int i = 0; i < 16; ++i) { acc[i][0] = b0; acc[i][1] = bb; } }
    for (int k = 0; k < TWO_D; k += 4) {
        float wa[4], wb[4];
        #pragma unroll
        for (int j = 0; j < 4; ++j) { wa[j] = U1[(k + j) * D + c]; wb[j] = U1[(k + j) * D + c + 64]; }
        #pragma unroll
        for (int i = 0; i < 16; ++i) {
            const float4 xv = *reinterpret_cast<const float4*>(&smem[(eg * 16 + i) * TWO_D + k]);
            acc[i][0] = fmaf(xv.x, wa[0], acc[i][0]); acc[i][1] = fmaf(xv.x, wb[0], acc[i][1]);
            acc[i][0] = fmaf(xv.y, wa[1], acc[i][0]); acc[i][1] = fmaf(xv.y, wb[1], acc[i][1]);
            acc[i][0] = fmaf(xv.z, wa[2], acc[i][0]); acc[i][1] = fmaf(xv.z, wb[2], acc[i][1]);
            acc[i][0] = fmaf(xv.w, wa[3], acc[i][0]); acc[i][1] = fmaf(xv.w, wb[3], acc[i][1]);
        }
    }
    __syncthreads();
    #pragma unroll
    for (int i = 0; i < 16; ++i) {
        int e = eg * 16 + i;
        smem[e * D + c] = fmaxf(acc[i][0], 0.f);
        smem[e * D + c + 64] = fmaxf(acc[i][1], 0.f);
    }
    __syncthreads();
    float acc2[16][2];
    { float b0 = ub2[c], bb = ub2[c + 64];
      #pragma unroll
      for (int i = 0; i < 16; ++i) { acc2[i][0] = b0; acc2[i][1] = bb; } }
    for (int k = 0; k < D; k += 4) {
        float wa[4], wb[4];
        #pragma unroll
        for (int j = 0; j < 4; ++j) { wa[j] = U2[(k + j) * D + c]; wb[j] = U2[(k + j) * D + c + 64]; }
        #pragma unroll
        for (int i = 0; i < 16; ++i) {
            const float4 hv = *reinterpret_cast<const float4*>(&smem[(eg * 16 + i) * D + k]);
            acc2[i][0] = fmaf(hv.x, wa[0], acc2[i][0]); acc2[i][1] = fmaf(hv.x, wb[0], acc2[i][1]);
            acc2[i][0] = fmaf(hv.y, wa[1], acc2[i][0]); acc2[i][1] = fmaf(hv.y, wb[1], acc2[i][1]);
            acc2[i][0] = fmaf(hv.z, wa[2], acc2[i][0]); acc2[i][1] = fmaf(hv.z, wb[2], acc2[i][1]);
            acc2[i][0] = fmaf(hv.w, wa[3], acc2[i][0]); acc2[i][1] = fmaf(hv.w, wb[3], acc2[i][1]);
        }
    }
    #pragma unroll
    for (int i = 0; i < 16; ++i) {
        int n = n0 + eg * 16 + i;
        if (n < N_NODES) {
            node_out[(size_t)n * D + c]      = acc2[i][0];
            node_out[(size_t)n * D + c + 64] = acc2[i][1];
        }
    }
}

extern "C" void kernel_launch(void* const* d_in, const int* in_sizes, int n_in,
                              void* d_out, int out_size, void* d_ws, size_t ws_size,
                              hipStream_t stream) {
    const float* node_latents = (const float*)d_in[0];
    const float* edge_latents = (const float*)d_in[1];
    const int*   edge_index   = (const int*)  d_in[2];
    const float* W1  = (const float*)d_in[3];
    const float* b1  = (const float*)d_in[4];
    const float* W2  = (const float*)d_in[5];
    const float* b2  = (const float*)d_in[6];
    const float* U1  = (const float*)d_in[7];
    const float* ub1 = (const float*)d_in[8];
    const float* U2  = (const float*)d_in[9];
    const float* ub2 = (const float*)d_in[10];

    float* out      = (float*)d_out;
    float* node_out = out;                               // [N*D]
    float* edge_out = out + (size_t)N_NODES * D;         // [E*D]
    const int* senders   = edge_index;
    const int* receivers = edge_index + N_EDGES;

    hipMemsetAsync(node_out, 0, (size_t)N_NODES * D * sizeof(float), stream);

    dim3 ge((N_EDGES + TM - 1) / TM);
    dim3 gn((N_NODES + TM - 1) / TM);

    // ws: w1f hi/lo (32768 ea) | w2f hi/lo (16384 ea) | u1f hi/lo | u2f hi/lo
    const size_t WS_NEED = (size_t)(2 * (32768 + 16384) * 2) * sizeof(ushort_t);
    if (ws_size >= WS_NEED) {
        ushort_t* w1f_hi = (ushort_t*)d_ws;
        ushort_t* w1f_lo = w1f_hi + 32768;
        ushort_t* w2f_hi = w1f_lo + 32768;
        ushort_t* w2f_lo = w2f_hi + 16384;
        ushort_t* u1f_hi = w2f_lo + 16384;
        ushort_t* u1f_lo = u1f_hi + 32768;
        ushort_t* u2f_hi = u1f_lo + 32768;
        ushort_t* u2f_lo = u2f_hi + 16384;
        prep_weights<<<dim3(384), dim3(256), 0, stream>>>(
            W1, W2, U1, U2,
            w1f_hi, w1f_lo, w2f_hi, w2f_lo, u1f_hi, u1f_lo, u2f_hi, u2f_lo);
        edge_kernel_mfma<<<ge, dim3(512), 0, stream>>>(
            node_latents, edge_latents, senders, receivers,
            w1f_hi, w1f_lo, w2f_hi, w2f_lo, b1, b2,
            node_out /*agg*/, edge_out);
        node_kernel_mfma<<<gn, dim3(512), 0, stream>>>(
            node_latents, node_out /*agg*/,
            u1f_hi, u1f_lo, u2f_hi, u2f_lo, ub1, ub2, node_out);
    } else {
        edge_kernel_fp32<<<ge, dim3(256), 0, stream>>>(
            node_latents, edge_latents, senders, receivers,
            W1, b1, W2, b2, node_out /*agg*/, edge_out);
        node_kernel_fp32<<<gn, dim3(256), 0, stream>>>(
            node_latents, node_out /*agg*/, U1, ub1, U2, ub2, node_out);
    }
}